// Round 1
// baseline (163.431 us; speedup 1.0000x reference)
//
#include <hip/hip_runtime.h>
#include <hip/hip_bf16.h>

#define Bdim 16
#define Cdim 512
#define Mdim 256
#define Ndim 4096

typedef short bf16x8 __attribute__((ext_vector_type(8)));
typedef float f32x4 __attribute__((ext_vector_type(4)));
typedef unsigned short us8 __attribute__((ext_vector_type(8)));
typedef unsigned short us4 __attribute__((ext_vector_type(4)));

__device__ __forceinline__ unsigned short f2b(float f) {
  union { float f; unsigned int u; } v; v.f = f;
  unsigned int u = v.u + 0x7fffu + ((v.u >> 16) & 1u);
  return (unsigned short)(u >> 16);
}
__device__ __forceinline__ float b2f(unsigned short h) {
  union { unsigned int u; float f; } v; v.u = ((unsigned int)h) << 16;
  return v.f;
}

// ---------------- K1: S[b,m,n] = sum_c Wk[m,c] * x[b,c,n]  (bf16 MFMA) ----
#define K1_PB 72
#define K1_PX 68

__global__ __launch_bounds__(256) void k1_gemm1(
    const float* __restrict__ gx, const float* __restrict__ gWk,
    unsigned short* __restrict__ gS) {
  __shared__ unsigned short Wk_s[64 * K1_PB];
  __shared__ unsigned short x_s[64 * K1_PX];
  const int t = threadIdx.x;
  const int b = blockIdx.z;
  const int m0 = blockIdx.y * 64;
  const int n0 = blockIdx.x * 64;
  const int w = t >> 6;
  const int lane = t & 63;
  const int lr = lane & 15;   // row (A) / col (B,D) within fragment
  const int lg = lane >> 4;   // k-group
  const int wm = (w >> 1) * 32;
  const int wn = (w & 1) * 32;

  f32x4 acc[2][2] = {};
  const float* xb = gx + (size_t)b * Cdim * Ndim;

  for (int ck = 0; ck < Cdim; ck += 64) {
    // stage Wk[m0..m0+63][ck..ck+63] -> bf16 LDS (row-major, k contiguous)
#pragma unroll
    for (int i = 0; i < 4; ++i) {
      int q = i * 256 + t;
      int r = q >> 4;
      int cq = (q & 15) * 4;
      f32x4 v = *reinterpret_cast<const f32x4*>(gWk + (size_t)(m0 + r) * Cdim + ck + cq);
      us4 h;
      h[0] = f2b(v[0]); h[1] = f2b(v[1]); h[2] = f2b(v[2]); h[3] = f2b(v[3]);
      *reinterpret_cast<us4*>(&Wk_s[r * K1_PB + cq]) = h;
    }
    // stage x[b][ck..ck+63][n0..n0+63] -> bf16 LDS [c][n]
#pragma unroll
    for (int i = 0; i < 4; ++i) {
      int q = i * 256 + t;
      int c = q >> 4;
      int nq = (q & 15) * 4;
      f32x4 v = *reinterpret_cast<const f32x4*>(xb + (size_t)(ck + c) * Ndim + n0 + nq);
      us4 h;
      h[0] = f2b(v[0]); h[1] = f2b(v[1]); h[2] = f2b(v[2]); h[3] = f2b(v[3]);
      *reinterpret_cast<us4*>(&x_s[c * K1_PX + nq]) = h;
    }
    __syncthreads();
#pragma unroll
    for (int kk = 0; kk < 64; kk += 32) {
      bf16x8 af[2];
#pragma unroll
      for (int mi = 0; mi < 2; ++mi)
        af[mi] = *reinterpret_cast<const bf16x8*>(
            &Wk_s[(wm + mi * 16 + lr) * K1_PB + kk + lg * 8]);
#pragma unroll
      for (int ni = 0; ni < 2; ++ni) {
        bf16x8 bfr;
        const int col = wn + ni * 16 + lr;
#pragma unroll
        for (int j = 0; j < 8; ++j)
          bfr[j] = (short)x_s[(kk + lg * 8 + j) * K1_PX + col];
#pragma unroll
        for (int mi = 0; mi < 2; ++mi)
          acc[mi][ni] = __builtin_amdgcn_mfma_f32_16x16x32_bf16(
              af[mi], bfr, acc[mi][ni], 0, 0, 0);
      }
    }
    __syncthreads();
  }
  unsigned short* Sb = gS + ((size_t)b * Mdim + m0) * Ndim + n0;
#pragma unroll
  for (int mi = 0; mi < 2; ++mi)
#pragma unroll
    for (int ni = 0; ni < 2; ++ni)
#pragma unroll
      for (int r = 0; r < 4; ++r) {
        int m = wm + mi * 16 + lg * 4 + r;   // D: row=(lane>>4)*4+reg
        int n = wn + ni * 16 + lr;           //    col=lane&15
        Sb[(size_t)m * Ndim + n] = f2b(acc[mi][ni][r]);
      }
}

// ---------------- K2: per-(b,m) row max and 1/sum(exp) ---------------------
__global__ __launch_bounds__(256) void k2_rowstats(
    const unsigned short* __restrict__ gS, float2* __restrict__ stats) {
  const int m = blockIdx.x;
  const int b = blockIdx.y;
  const unsigned short* row = gS + ((size_t)b * Mdim + m) * Ndim;
  const int t = threadIdx.x;
  const int w = t >> 6;
  float v[16];
#pragma unroll
  for (int i = 0; i < 2; ++i) {
    us8 u = *reinterpret_cast<const us8*>(row + i * 2048 + t * 8);
#pragma unroll
    for (int j = 0; j < 8; ++j) v[i * 8 + j] = b2f(u[j]);
  }
  float mx = -1e30f;
#pragma unroll
  for (int i = 0; i < 16; ++i) mx = fmaxf(mx, v[i]);
#pragma unroll
  for (int o = 32; o > 0; o >>= 1) mx = fmaxf(mx, __shfl_xor(mx, o, 64));
  __shared__ float redmax[4], redsum[4];
  if ((t & 63) == 0) redmax[w] = mx;
  __syncthreads();
  mx = fmaxf(fmaxf(redmax[0], redmax[1]), fmaxf(redmax[2], redmax[3]));
  float s = 0.f;
#pragma unroll
  for (int i = 0; i < 16; ++i) s += __expf(v[i] - mx);
#pragma unroll
  for (int o = 32; o > 0; o >>= 1) s += __shfl_xor(s, o, 64);
  if ((t & 63) == 0) redsum[w] = s;
  __syncthreads();
  if (t == 0) {
    float tot = redsum[0] + redsum[1] + redsum[2] + redsum[3];
    stats[(size_t)b * Mdim + m] = make_float2(mx, 1.0f / tot);
  }
}

// ---------------- K3: P = softmax, L1-normalize over M, write PT[b][n][m] --
__global__ __launch_bounds__(256) void k3_norm(
    const unsigned short* __restrict__ gS, const float2* __restrict__ stats,
    unsigned short* __restrict__ gPT) {
  const int b = blockIdx.y;
  const int n0 = blockIdx.x * 64;
  __shared__ unsigned short P_s[256 * 66];
  __shared__ float cs[4][64];
  __shared__ float rtot[64];
  const int t = threadIdx.x;
  const int w = t >> 6;
  const int l = t & 63;
  float acc = 0.f;
  const unsigned short* Sb = gS + (size_t)b * Mdim * Ndim + n0;
#pragma unroll 4
  for (int i = 0; i < 64; ++i) {
    int m = i * 4 + w;
    float2 st = stats[b * Mdim + m];
    float p = __expf(b2f(Sb[(size_t)m * Ndim + l]) - st.x) * st.y;
    acc += p;
    P_s[m * 66 + l] = f2b(p);
  }
  cs[w][l] = acc;
  __syncthreads();
  if (w == 0) rtot[l] = 1.0f / (1e-9f + cs[0][l] + cs[1][l] + cs[2][l] + cs[3][l]);
  __syncthreads();
  const int n = t >> 2;
  const int mb = (t & 3) * 64;
  const float rc = rtot[n];
  unsigned short* dst = gPT + ((size_t)b * Ndim + n0 + n) * Mdim + mb;
#pragma unroll
  for (int j = 0; j < 64; j += 8) {
    us8 pk;
#pragma unroll
    for (int jj = 0; jj < 8; ++jj)
      pk[jj] = f2b(b2f(P_s[(mb + j + jj) * 66 + n]) * rc);
    *reinterpret_cast<us8*>(dst + j) = pk;
  }
}

// ---------------- K4: out = x + Wv * Pn  (bf16 MFMA, residual fused) -------
#define K4_P 136

__global__ __launch_bounds__(256) void k4_gemm2(
    const float* __restrict__ gx, const float* __restrict__ gWv,
    const unsigned short* __restrict__ gPT, float* __restrict__ gout) {
  __shared__ unsigned short Wv_s[64 * K4_P];
  __shared__ unsigned short PT_s[64 * K4_P];
  const int t = threadIdx.x;
  const int b = blockIdx.z;
  const int c0 = blockIdx.y * 64;
  const int n0 = blockIdx.x * 64;
  const int w = t >> 6;
  const int lane = t & 63;
  const int lr = lane & 15;
  const int lg = lane >> 4;
  const int wc = (w >> 1) * 32;
  const int wn = (w & 1) * 32;

  f32x4 acc[2][2] = {};

  for (int ck = 0; ck < Mdim; ck += 128) {
    // stage Wv[c0..+63][ck..ck+127] f32 -> bf16
#pragma unroll
    for (int i = 0; i < 8; ++i) {
      int q = i * 256 + t;
      int r = q >> 5;
      int mq = (q & 31) * 4;
      f32x4 v = *reinterpret_cast<const f32x4*>(gWv + (size_t)(c0 + r) * Mdim + ck + mq);
      us4 h;
      h[0] = f2b(v[0]); h[1] = f2b(v[1]); h[2] = f2b(v[2]); h[3] = f2b(v[3]);
      *reinterpret_cast<us4*>(&Wv_s[r * K4_P + mq]) = h;
    }
    // stage PT[b][n0..+63][ck..ck+127] (already bf16)
#pragma unroll
    for (int i = 0; i < 4; ++i) {
      int q = i * 256 + t;
      int r = q >> 4;
      int mq = (q & 15) * 8;
      us8 u = *reinterpret_cast<const us8*>(gPT + ((size_t)b * Ndim + n0 + r) * Mdim + ck + mq);
      *reinterpret_cast<us8*>(&PT_s[r * K4_P + mq]) = u;
    }
    __syncthreads();
#pragma unroll
    for (int kk = 0; kk < 128; kk += 32) {
      bf16x8 af[2], bfr[2];
#pragma unroll
      for (int ci = 0; ci < 2; ++ci)
        af[ci] = *reinterpret_cast<const bf16x8*>(
            &Wv_s[(wc + ci * 16 + lr) * K4_P + kk + lg * 8]);
#pragma unroll
      for (int ni = 0; ni < 2; ++ni)
        bfr[ni] = *reinterpret_cast<const bf16x8*>(
            &PT_s[(wn + ni * 16 + lr) * K4_P + kk + lg * 8]);
#pragma unroll
      for (int ci = 0; ci < 2; ++ci)
#pragma unroll
        for (int ni = 0; ni < 2; ++ni)
          acc[ci][ni] = __builtin_amdgcn_mfma_f32_16x16x32_bf16(
              af[ci], bfr[ni], acc[ci][ni], 0, 0, 0);
    }
    __syncthreads();
  }
#pragma unroll
  for (int ci = 0; ci < 2; ++ci)
#pragma unroll
    for (int ni = 0; ni < 2; ++ni)
#pragma unroll
      for (int r = 0; r < 4; ++r) {
        int c = c0 + wc + ci * 16 + lg * 4 + r;
        int n = n0 + wn + ni * 16 + lr;
        size_t idx = ((size_t)b * Cdim + c) * Ndim + n;
        gout[idx] = gx[idx] + acc[ci][ni][r];
      }
}

extern "C" void kernel_launch(void* const* d_in, const int* in_sizes, int n_in,
                              void* d_out, int out_size, void* d_ws, size_t ws_size,
                              hipStream_t stream) {
  const float* x = (const float*)d_in[0];
  const float* Wk = (const float*)d_in[1];
  const float* Wv = (const float*)d_in[2];
  float* out = (float*)d_out;

  unsigned short* S = (unsigned short*)d_ws;                       // [B][M][N] bf16
  unsigned short* PT = S + (size_t)Bdim * Mdim * Ndim;             // [B][N][M] bf16
  float2* stats = (float2*)(PT + (size_t)Bdim * Ndim * Mdim);      // [B][M] (max, 1/sum)

  k1_gemm1<<<dim3(Ndim / 64, Mdim / 64, Bdim), 256, 0, stream>>>(x, Wk, S);
  k2_rowstats<<<dim3(Mdim, Bdim), 256, 0, stream>>>(S, stats);
  k3_norm<<<dim3(Ndim / 64, Bdim), 256, 0, stream>>>(S, stats, PT);
  k4_gemm2<<<dim3(Ndim / 64, Cdim / 64, Bdim), 256, 0, stream>>>(x, Wv, PT, out);
}

// Round 2
// 135.074 us; speedup vs baseline: 1.2099x; 1.2099x over previous
//
#include <hip/hip_runtime.h>
#include <hip/hip_bf16.h>

#define Bdim 16
#define Cdim 512
#define Mdim 256
#define Ndim 4096

typedef short bf16x8 __attribute__((ext_vector_type(8)));
typedef float f32x4 __attribute__((ext_vector_type(4)));
typedef unsigned short us8 __attribute__((ext_vector_type(8)));
typedef unsigned short us4 __attribute__((ext_vector_type(4)));

// round-half-up f32 -> bf16 (2 VALU); tie bias only vs RNE
__device__ __forceinline__ unsigned short f2b(float f) {
  union { float f; unsigned int u; } v; v.f = f;
  return (unsigned short)((v.u + 0x8000u) >> 16);
}
__device__ __forceinline__ float b2f(unsigned short h) {
  union { unsigned int u; float f; } v; v.u = ((unsigned int)h) << 16;
  return v.f;
}

// ---------------- K1: S[b,m,n] = sum_c Wk[m,c] * x[b,c,n]  (bf16 MFMA) ----
// 128x128 tile, BK=64, 4 waves (2x2), each wave 64x64 via 4x4 frags 16x16x32.
// Both LDS tiles row-padded to 72 shorts (144B): 16B-aligned b128 ops,
// conflict-free (bank quad = (row+klane) mod 8, uniform).
#define K1_PAD 72

__global__ __launch_bounds__(256) void k1_gemm1(
    const float* __restrict__ gx, const float* __restrict__ gWk,
    unsigned short* __restrict__ gS) {
  __shared__ unsigned short Wk_s[128 * K1_PAD];   // [m][c]
  __shared__ unsigned short xT_s[128 * K1_PAD];   // [n][c]  (transposed!)
  const int t = threadIdx.x;
  const int b = blockIdx.z;
  const int m0 = blockIdx.y * 128;
  const int n0 = blockIdx.x * 128;
  const int w = t >> 6;
  const int lane = t & 63;
  const int lr = lane & 15;   // A-row / B-col within fragment
  const int lg = lane >> 4;   // k-group
  const int wm = (w >> 1) * 64;
  const int wn = (w & 1) * 64;

  f32x4 acc[4][4] = {};
  const float* xb = gx + (size_t)b * Cdim * Ndim;

  for (int ck = 0; ck < Cdim; ck += 64) {
    // --- stage Wk[m0..+127][ck..+63] -> bf16 LDS [m][c] via b128 writes
#pragma unroll
    for (int i = 0; i < 4; ++i) {
      int q = i * 256 + t;
      int r = q >> 3;            // 0..127
      int c8 = (q & 7) * 8;      // 0..56
      const float* src = gWk + (size_t)(m0 + r) * Cdim + ck + c8;
      f32x4 v0 = *reinterpret_cast<const f32x4*>(src);
      f32x4 v1 = *reinterpret_cast<const f32x4*>(src + 4);
      us8 h;
      h[0] = f2b(v0[0]); h[1] = f2b(v0[1]); h[2] = f2b(v0[2]); h[3] = f2b(v0[3]);
      h[4] = f2b(v1[0]); h[5] = f2b(v1[1]); h[6] = f2b(v1[2]); h[7] = f2b(v1[3]);
      *reinterpret_cast<us8*>(&Wk_s[r * K1_PAD + c8]) = h;
    }
    // --- stage x[ck..+63][n0..+127] -> bf16 LDS transposed [n][c]
    // thread: n = (t&63)+64h, c-block = (t>>6)*16; 16 coalesced scalar f32
    // loads down the c-column, pack, 2x ds_write_b128.
    {
      const int nl = t & 63;
      const int cb = (t >> 6) * 16;
#pragma unroll
      for (int h = 0; h < 2; ++h) {
        const int n = nl + h * 64;
        const float* src = xb + (size_t)(ck + cb) * Ndim + n0 + n;
        float xv[16];
#pragma unroll
        for (int j = 0; j < 16; ++j) xv[j] = src[(size_t)j * Ndim];
        us8 h0, h1;
#pragma unroll
        for (int j = 0; j < 8; ++j) { h0[j] = f2b(xv[j]); h1[j] = f2b(xv[8 + j]); }
        *reinterpret_cast<us8*>(&xT_s[n * K1_PAD + cb]) = h0;
        *reinterpret_cast<us8*>(&xT_s[n * K1_PAD + cb + 8]) = h1;
      }
    }
    __syncthreads();
#pragma unroll
    for (int kk = 0; kk < 64; kk += 32) {
      bf16x8 af[4], bfr[4];
#pragma unroll
      for (int mi = 0; mi < 4; ++mi)
        af[mi] = *reinterpret_cast<const bf16x8*>(
            &Wk_s[(wm + mi * 16 + lr) * K1_PAD + kk + lg * 8]);
#pragma unroll
      for (int ni = 0; ni < 4; ++ni)
        bfr[ni] = *reinterpret_cast<const bf16x8*>(
            &xT_s[(wn + ni * 16 + lr) * K1_PAD + kk + lg * 8]);
#pragma unroll
      for (int mi = 0; mi < 4; ++mi)
#pragma unroll
        for (int ni = 0; ni < 4; ++ni)
          acc[mi][ni] = __builtin_amdgcn_mfma_f32_16x16x32_bf16(
              af[mi], bfr[ni], acc[mi][ni], 0, 0, 0);
    }
    __syncthreads();
  }
  unsigned short* Sb = gS + ((size_t)b * Mdim + m0 + wm) * Ndim + n0 + wn;
#pragma unroll
  for (int mi = 0; mi < 4; ++mi)
#pragma unroll
    for (int ni = 0; ni < 4; ++ni)
#pragma unroll
      for (int r = 0; r < 4; ++r) {
        int m = mi * 16 + lg * 4 + r;   // D: row=(lane>>4)*4+reg
        int n = ni * 16 + lr;           //    col=lane&15
        Sb[(size_t)m * Ndim + n] = f2b(acc[mi][ni][r]);
      }
}

// ---------------- K2: per-(b,m) row max and 1/sum(exp) ---------------------
__global__ __launch_bounds__(256) void k2_rowstats(
    const unsigned short* __restrict__ gS, float2* __restrict__ stats) {
  const int m = blockIdx.x;
  const int b = blockIdx.y;
  const unsigned short* row = gS + ((size_t)b * Mdim + m) * Ndim;
  const int t = threadIdx.x;
  const int w = t >> 6;
  float v[16];
#pragma unroll
  for (int i = 0; i < 2; ++i) {
    us8 u = *reinterpret_cast<const us8*>(row + i * 2048 + t * 8);
#pragma unroll
    for (int j = 0; j < 8; ++j) v[i * 8 + j] = b2f(u[j]);
  }
  float mx = -1e30f;
#pragma unroll
  for (int i = 0; i < 16; ++i) mx = fmaxf(mx, v[i]);
#pragma unroll
  for (int o = 32; o > 0; o >>= 1) mx = fmaxf(mx, __shfl_xor(mx, o, 64));
  __shared__ float redmax[4], redsum[4];
  if ((t & 63) == 0) redmax[w] = mx;
  __syncthreads();
  mx = fmaxf(fmaxf(redmax[0], redmax[1]), fmaxf(redmax[2], redmax[3]));
  float s = 0.f;
#pragma unroll
  for (int i = 0; i < 16; ++i) s += __expf(v[i] - mx);
#pragma unroll
  for (int o = 32; o > 0; o >>= 1) s += __shfl_xor(s, o, 64);
  if ((t & 63) == 0) redsum[w] = s;
  __syncthreads();
  if (t == 0) {
    float tot = redsum[0] + redsum[1] + redsum[2] + redsum[3];
    stats[(size_t)b * Mdim + m] = make_float2(mx, 1.0f / tot);
  }
}

// ---------------- K3: P = softmax, L1-normalize over M, write PT[b][n][m] --
__global__ __launch_bounds__(256) void k3_norm(
    const unsigned short* __restrict__ gS, const float2* __restrict__ stats,
    unsigned short* __restrict__ gPT) {
  const int b = blockIdx.y;
  const int n0 = blockIdx.x * 64;
  __shared__ unsigned short P_s[256 * 66];
  __shared__ float cs[4][64];
  __shared__ float rtot[64];
  const int t = threadIdx.x;
  const int w = t >> 6;
  const int l = t & 63;
  float acc = 0.f;
  const unsigned short* Sb = gS + (size_t)b * Mdim * Ndim + n0;
#pragma unroll 4
  for (int i = 0; i < 64; ++i) {
    int m = i * 4 + w;
    float2 st = stats[b * Mdim + m];
    float p = __expf(b2f(Sb[(size_t)m * Ndim + l]) - st.x) * st.y;
    acc += p;
    P_s[m * 66 + l] = f2b(p);
  }
  cs[w][l] = acc;
  __syncthreads();
  if (w == 0) rtot[l] = 1.0f / (1e-9f + cs[0][l] + cs[1][l] + cs[2][l] + cs[3][l]);
  __syncthreads();
  const int n = t >> 2;
  const int mb = (t & 3) * 64;
  const float rc = rtot[n];
  unsigned short* dst = gPT + ((size_t)b * Ndim + n0 + n) * Mdim + mb;
#pragma unroll
  for (int j = 0; j < 64; j += 8) {
    us8 pk;
#pragma unroll
    for (int jj = 0; jj < 8; ++jj)
      pk[jj] = f2b(b2f(P_s[(mb + j + jj) * 66 + n]) * rc);
    *reinterpret_cast<us8*>(dst + j) = pk;
  }
}

// ---------------- K4: out = x + Wv * Pn  (bf16 MFMA, residual fused) -------
#define K4_P 136

__global__ __launch_bounds__(256) void k4_gemm2(
    const float* __restrict__ gx, const float* __restrict__ gWv,
    const unsigned short* __restrict__ gPT, float* __restrict__ gout) {
  __shared__ unsigned short Wv_s[64 * K4_P];
  __shared__ unsigned short PT_s[64 * K4_P];
  const int t = threadIdx.x;
  const int b = blockIdx.z;
  const int c0 = blockIdx.y * 64;
  const int n0 = blockIdx.x * 64;
  const int w = t >> 6;
  const int lane = t & 63;
  const int lr = lane & 15;
  const int lg = lane >> 4;
  const int wc = (w >> 1) * 32;
  const int wn = (w & 1) * 32;

  f32x4 acc[2][2] = {};

  for (int ck = 0; ck < Mdim; ck += 128) {
    // stage Wv[c0..+63][ck..ck+127] f32 -> bf16
#pragma unroll
    for (int i = 0; i < 8; ++i) {
      int q = i * 256 + t;
      int r = q >> 5;
      int mq = (q & 31) * 4;
      f32x4 v = *reinterpret_cast<const f32x4*>(gWv + (size_t)(c0 + r) * Mdim + ck + mq);
      us4 h;
      h[0] = f2b(v[0]); h[1] = f2b(v[1]); h[2] = f2b(v[2]); h[3] = f2b(v[3]);
      *reinterpret_cast<us4*>(&Wv_s[r * K4_P + mq]) = h;
    }
    // stage PT[b][n0..+63][ck..ck+127] (already bf16)
#pragma unroll
    for (int i = 0; i < 4; ++i) {
      int q = i * 256 + t;
      int r = q >> 4;
      int mq = (q & 15) * 8;
      us8 u = *reinterpret_cast<const us8*>(gPT + ((size_t)b * Ndim + n0 + r) * Mdim + ck + mq);
      *reinterpret_cast<us8*>(&PT_s[r * K4_P + mq]) = u;
    }
    __syncthreads();
#pragma unroll
    for (int kk = 0; kk < 128; kk += 32) {
      bf16x8 af[2], bfr[2];
#pragma unroll
      for (int ci = 0; ci < 2; ++ci)
        af[ci] = *reinterpret_cast<const bf16x8*>(
            &Wv_s[(wc + ci * 16 + lr) * K4_P + kk + lg * 8]);
#pragma unroll
      for (int ni = 0; ni < 2; ++ni)
        bfr[ni] = *reinterpret_cast<const bf16x8*>(
            &PT_s[(wn + ni * 16 + lr) * K4_P + kk + lg * 8]);
#pragma unroll
      for (int ci = 0; ci < 2; ++ci)
#pragma unroll
        for (int ni = 0; ni < 2; ++ni)
          acc[ci][ni] = __builtin_amdgcn_mfma_f32_16x16x32_bf16(
              af[ci], bfr[ni], acc[ci][ni], 0, 0, 0);
    }
    __syncthreads();
  }
#pragma unroll
  for (int ci = 0; ci < 2; ++ci)
#pragma unroll
    for (int ni = 0; ni < 2; ++ni)
#pragma unroll
      for (int r = 0; r < 4; ++r) {
        int c = c0 + wc + ci * 16 + lg * 4 + r;
        int n = n0 + wn + ni * 16 + lr;
        size_t idx = ((size_t)b * Cdim + c) * Ndim + n;
        gout[idx] = gx[idx] + acc[ci][ni][r];
      }
}

extern "C" void kernel_launch(void* const* d_in, const int* in_sizes, int n_in,
                              void* d_out, int out_size, void* d_ws, size_t ws_size,
                              hipStream_t stream) {
  const float* x = (const float*)d_in[0];
  const float* Wk = (const float*)d_in[1];
  const float* Wv = (const float*)d_in[2];
  float* out = (float*)d_out;

  unsigned short* S = (unsigned short*)d_ws;                       // [B][M][N] bf16
  unsigned short* PT = S + (size_t)Bdim * Mdim * Ndim;             // [B][N][M] bf16
  float2* stats = (float2*)(PT + (size_t)Bdim * Ndim * Mdim);      // [B][M] (max, 1/sum)

  k1_gemm1<<<dim3(Ndim / 128, Mdim / 128, Bdim), 256, 0, stream>>>(x, Wk, S);
  k2_rowstats<<<dim3(Mdim, Bdim), 256, 0, stream>>>(S, stats);
  k3_norm<<<dim3(Ndim / 64, Bdim), 256, 0, stream>>>(S, stats, PT);
  k4_gemm2<<<dim3(Ndim / 64, Cdim / 64, Bdim), 256, 0, stream>>>(x, Wv, PT, out);
}